// Round 1
// baseline (393.932 us; speedup 1.0000x reference)
//
#include <hip/hip_runtime.h>
#include <math.h>

#define BB   8
#define NN   2048
#define CINC 128
#define COU  256
#define KNNK 16
#define REVCAP 64

static __device__ __forceinline__ unsigned long long umin64(unsigned long long a, unsigned long long b) {
    return a < b ? a : b;
}

// ---------------- transpose features (B,C,N) -> fT (B,N,C) ----------------
__global__ __launch_bounds__(256) void transpose_kernel(const float* __restrict__ feat,
                                                        float* __restrict__ fT) {
    __shared__ float t[32][33];
    int b  = blockIdx.z;
    int n0 = blockIdx.x * 32, c0 = blockIdx.y * 32;
    int tx = threadIdx.x, ty = threadIdx.y;  // (32,8)
#pragma unroll
    for (int i = 0; i < 4; i++)
        t[ty + i * 8][tx] = feat[((size_t)b * CINC + c0 + ty + i * 8) * NN + n0 + tx];
    __syncthreads();
#pragma unroll
    for (int i = 0; i < 4; i++)
        fT[((size_t)b * NN + n0 + ty + i * 8) * CINC + c0 + tx] = t[tx][ty + i * 8];
}

// ---------------- KNN: block per (b,n) ----------------
// Replicates reference arithmetic:
//   sq  = (x*x + y*y) + z*z                 (plain rn ops, no FMA)
//   dot = fma(z,z', fma(y,y', rn(x*x')))    (FMA chain, ascending k)
//   dist = (sq_n + sq_m) - 2*dot            (plain rn ops)
// top-k smallest with tie-break on lowest index (lax.top_k stability).
__global__ __launch_bounds__(256) void knn_kernel(const float* __restrict__ xyz,
                                                  int* __restrict__ knn_idx,
                                                  int* __restrict__ revcnt,
                                                  int* __restrict__ rev) {
    __shared__ float lx[NN], ly[NN], lz[NN], lsq[NN];
    __shared__ float ldist[NN];
    __shared__ unsigned long long wred[4];
    __shared__ int selbuf[KNNK];

    int b = blockIdx.x >> 11;
    int n = blockIdx.x & (NN - 1);
    int tid = threadIdx.x;

    const float* xb = xyz + (size_t)b * 3 * NN;
    for (int m = tid; m < NN; m += 256) {
        float x = xb[m], y = xb[NN + m], z = xb[2 * NN + m];
        lx[m] = x; ly[m] = y; lz[m] = z;
        lsq[m] = __fadd_rn(__fadd_rn(__fmul_rn(x, x), __fmul_rn(y, y)), __fmul_rn(z, z));
    }
    __syncthreads();

    float qx = lx[n], qy = ly[n], qz = lz[n], qsq = lsq[n];
    for (int m = tid; m < NN; m += 256) {
        float dot = fmaf(qz, lz[m], fmaf(qy, ly[m], __fmul_rn(qx, lx[m])));
        ldist[m] = __fsub_rn(__fadd_rn(qsq, lsq[m]), __fmul_rn(2.0f, dot));
    }
    __syncthreads();

    for (int k = 0; k < KNNK; k++) {
        unsigned long long best = ~0ull;
#pragma unroll
        for (int j = 0; j < NN / 256; j++) {
            int m = tid + j * 256;
            unsigned int u = __float_as_uint(ldist[m]);
            u = (u & 0x80000000u) ? ~u : (u | 0x80000000u);
            unsigned long long key = ((unsigned long long)u << 32) | (unsigned int)m;
            best = umin64(best, key);
        }
#pragma unroll
        for (int off = 32; off; off >>= 1)
            best = umin64(best, (unsigned long long)__shfl_xor(best, off, 64));
        if ((tid & 63) == 0) wred[tid >> 6] = best;
        __syncthreads();
        if (tid == 0) {
            unsigned long long w = umin64(umin64(wred[0], wred[1]), umin64(wred[2], wred[3]));
            int wm = (int)(w & 0xffffffffull);
            selbuf[k] = wm;
            ldist[wm] = __uint_as_float(0x7f800000u);  // +inf, exclude from next rounds
        }
        __syncthreads();
    }

    if (tid < KNNK) {
        int m = selbuf[tid];
        knn_idx[(size_t)blockIdx.x * KNNK + tid] = m;
        int pos = atomicAdd(&revcnt[b * NN + m], 1);
        if (pos < REVCAP) rev[((size_t)b * NN + m) * REVCAP + pos] = n;
    }
}

// ---------------- dinv = rsqrt(D + 1e-6), D = 0.5*(K + indeg) ----------------
__global__ __launch_bounds__(256) void dinv_kernel(const int* __restrict__ revcnt,
                                                   float* __restrict__ dinv) {
    int i = blockIdx.x * 256 + threadIdx.x;
    if (i < BB * NN) {
        float D = 0.5f * (float)(KNNK + revcnt[i]);
        dinv[i] = 1.0f / sqrtf(D + 1e-6f);
    }
}

// ---------------- spec[c,n] = f[c,n] - d_n * sum_j 0.5*d_mj * f[c,mj] ----------------
__global__ __launch_bounds__(128) void spec_kernel(const float* __restrict__ fT,
                                                   const int* __restrict__ knn_idx,
                                                   const int* __restrict__ revcnt,
                                                   const int* __restrict__ rev,
                                                   const float* __restrict__ dinv,
                                                   float* __restrict__ specT) {
    __shared__ int ml[KNNK + REVCAP];
    __shared__ float wl[KNNK + REVCAP];
    __shared__ int s_cnt;

    int bn = blockIdx.x;           // b*NN + n
    int b = bn >> 11;
    int tid = threadIdx.x;

    if (tid == 0) {
        int c = revcnt[bn];
        s_cnt = c < REVCAP ? c : REVCAP;
    }
    __syncthreads();
    int cnt = s_cnt;
    if (tid < KNNK) ml[tid] = knn_idx[(size_t)bn * KNNK + tid];
    if (tid < cnt) ml[KNNK + tid] = rev[(size_t)bn * REVCAP + tid];
    __syncthreads();
    int total = KNNK + cnt;
    if (tid < total) wl[tid] = 0.5f * dinv[b * NN + ml[tid]];
    __syncthreads();

    float dn = dinv[bn];
    float acc = 0.0f;
    for (int j = 0; j < total; j++)
        acc = fmaf(wl[j], fT[((size_t)b * NN + ml[j]) * CINC + tid], acc);
    float f0 = fT[(size_t)bn * CINC + tid];
    specT[(size_t)bn * CINC + tid] = f0 - dn * acc;
}

// ---------------- GEMM1: g1 = gelu(bn(W_spec @ spec + b)) , layout (b,n,o) ----------------
__global__ __launch_bounds__(256) void gemm1_kernel(const float* __restrict__ specT,
                                                    const float* __restrict__ Wspec,
                                                    const float* __restrict__ bspec,
                                                    const float* __restrict__ gamma,
                                                    const float* __restrict__ beta,
                                                    const float* __restrict__ mean,
                                                    const float* __restrict__ var,
                                                    float* __restrict__ g1T) {
    __shared__ float Sa[64][65];
    __shared__ float Sb[64][65];
    int n0 = blockIdx.x * 64, o0 = blockIdx.y * 64, b = blockIdx.z;
    int tx = threadIdx.x, ty = threadIdx.y;
    int tid = ty * 16 + tx;

    float acc[4][4] = {};
    for (int kk = 0; kk < CINC; kk += 64) {
        __syncthreads();
        for (int i = tid; i < 64 * 64; i += 256) {
            int r = i >> 6, k = i & 63;
            Sa[r][k] = specT[((size_t)b * NN + n0 + r) * CINC + kk + k];
            Sb[r][k] = Wspec[(size_t)(o0 + r) * CINC + kk + k];
        }
        __syncthreads();
#pragma unroll 8
        for (int k = 0; k < 64; k++) {
            float a0 = Sa[ty * 4 + 0][k], a1 = Sa[ty * 4 + 1][k];
            float a2 = Sa[ty * 4 + 2][k], a3 = Sa[ty * 4 + 3][k];
            float w0 = Sb[tx * 4 + 0][k], w1 = Sb[tx * 4 + 1][k];
            float w2 = Sb[tx * 4 + 2][k], w3 = Sb[tx * 4 + 3][k];
            acc[0][0] = fmaf(a0, w0, acc[0][0]); acc[0][1] = fmaf(a0, w1, acc[0][1]);
            acc[0][2] = fmaf(a0, w2, acc[0][2]); acc[0][3] = fmaf(a0, w3, acc[0][3]);
            acc[1][0] = fmaf(a1, w0, acc[1][0]); acc[1][1] = fmaf(a1, w1, acc[1][1]);
            acc[1][2] = fmaf(a1, w2, acc[1][2]); acc[1][3] = fmaf(a1, w3, acc[1][3]);
            acc[2][0] = fmaf(a2, w0, acc[2][0]); acc[2][1] = fmaf(a2, w1, acc[2][1]);
            acc[2][2] = fmaf(a2, w2, acc[2][2]); acc[2][3] = fmaf(a2, w3, acc[2][3]);
            acc[3][0] = fmaf(a3, w0, acc[3][0]); acc[3][1] = fmaf(a3, w1, acc[3][1]);
            acc[3][2] = fmaf(a3, w2, acc[3][2]); acc[3][3] = fmaf(a3, w3, acc[3][3]);
        }
    }
#pragma unroll
    for (int j = 0; j < 4; j++) {
        int o = o0 + tx * 4 + j;
        float sc = 1.0f / sqrtf(var[o] + 1e-5f);
        float ga = gamma[o], be = beta[o], mu = mean[o], bs = bspec[o];
#pragma unroll
        for (int i = 0; i < 4; i++) {
            float y = acc[i][j] + bs;
            y = (y - mu) * sc;
            y = y * ga + be;
            float g = 0.5f * y * (1.0f + erff(y * 0.70710678118654752440f));
            g1T[((size_t)b * NN + n0 + ty * 4 + i) * COU + o] = g;
        }
    }
}

// ---------------- GEMM2: out[b,o,n] = W2[o,:] @ g1[b,n,:] + b2[o] ----------------
__global__ __launch_bounds__(256) void gemm2_kernel(const float* __restrict__ g1T,
                                                    const float* __restrict__ Wlow,
                                                    const float* __restrict__ blow,
                                                    const float* __restrict__ Whigh,
                                                    const float* __restrict__ bhigh,
                                                    float* __restrict__ out) {
    __shared__ float Ga[64][65];
    __shared__ float Wb[64][65];
    int n0 = blockIdx.x * 64, o0 = blockIdx.y * 64, b = blockIdx.z;
    int tx = threadIdx.x, ty = threadIdx.y;
    int tid = ty * 16 + tx;

    float acc[4][4] = {};
    for (int kk = 0; kk < COU; kk += 64) {
        __syncthreads();
        for (int i = tid; i < 64 * 64; i += 256) {
            int r = i >> 6, k = i & 63;
            Ga[r][k] = g1T[((size_t)b * NN + n0 + r) * COU + kk + k];
            int o = o0 + r;
            Wb[r][k] = (o < 128) ? Wlow[(size_t)o * COU + kk + k]
                                 : Whigh[(size_t)(o - 128) * COU + kk + k];
        }
        __syncthreads();
#pragma unroll 8
        for (int k = 0; k < 64; k++) {
            float a0 = Ga[ty * 4 + 0][k], a1 = Ga[ty * 4 + 1][k];
            float a2 = Ga[ty * 4 + 2][k], a3 = Ga[ty * 4 + 3][k];
            float w0 = Wb[tx * 4 + 0][k], w1 = Wb[tx * 4 + 1][k];
            float w2 = Wb[tx * 4 + 2][k], w3 = Wb[tx * 4 + 3][k];
            acc[0][0] = fmaf(a0, w0, acc[0][0]); acc[0][1] = fmaf(a0, w1, acc[0][1]);
            acc[0][2] = fmaf(a0, w2, acc[0][2]); acc[0][3] = fmaf(a0, w3, acc[0][3]);
            acc[1][0] = fmaf(a1, w0, acc[1][0]); acc[1][1] = fmaf(a1, w1, acc[1][1]);
            acc[1][2] = fmaf(a1, w2, acc[1][2]); acc[1][3] = fmaf(a1, w3, acc[1][3]);
            acc[2][0] = fmaf(a2, w0, acc[2][0]); acc[2][1] = fmaf(a2, w1, acc[2][1]);
            acc[2][2] = fmaf(a2, w2, acc[2][2]); acc[2][3] = fmaf(a2, w3, acc[2][3]);
            acc[3][0] = fmaf(a3, w0, acc[3][0]); acc[3][1] = fmaf(a3, w1, acc[3][1]);
            acc[3][2] = fmaf(a3, w2, acc[3][2]); acc[3][3] = fmaf(a3, w3, acc[3][3]);
        }
    }
#pragma unroll
    for (int j = 0; j < 4; j++) {
        int o = o0 + tx * 4 + j;
        float bias = (o < 128) ? blow[o] : bhigh[o - 128];
        float4 v;
        v.x = acc[0][j] + bias;
        v.y = acc[1][j] + bias;
        v.z = acc[2][j] + bias;
        v.w = acc[3][j] + bias;
        *(float4*)&out[((size_t)b * COU + o) * NN + n0 + ty * 4] = v;
    }
}

extern "C" void kernel_launch(void* const* d_in, const int* in_sizes, int n_in,
                              void* d_out, int out_size, void* d_ws, size_t ws_size,
                              hipStream_t stream) {
    const float* xyz      = (const float*)d_in[0];
    const float* features = (const float*)d_in[1];
    const float* W_spec   = (const float*)d_in[2];
    const float* b_spec   = (const float*)d_in[3];
    const float* bn_gamma = (const float*)d_in[4];
    const float* bn_beta  = (const float*)d_in[5];
    const float* bn_mean  = (const float*)d_in[6];
    const float* bn_var   = (const float*)d_in[7];
    const float* W_low    = (const float*)d_in[8];
    const float* b_low    = (const float*)d_in[9];
    const float* W_high   = (const float*)d_in[10];
    const float* b_high   = (const float*)d_in[11];
    float* out = (float*)d_out;

    char* ws = (char*)d_ws;
    size_t off = 0;
    float* fT    = (float*)(ws + off); off += (size_t)BB * NN * CINC * 4;   // 8 MB
    float* specT = (float*)(ws + off); off += (size_t)BB * NN * CINC * 4;   // 8 MB
    float* g1T   = (float*)(ws + off); off += (size_t)BB * NN * COU  * 4;   // 16 MB
    int*   idx   = (int*)  (ws + off); off += (size_t)BB * NN * KNNK * 4;   // 1 MB
    int*   rcnt  = (int*)  (ws + off); off += (size_t)BB * NN * 4;          // 64 KB
    int*   rev   = (int*)  (ws + off); off += (size_t)BB * NN * REVCAP * 4; // 4 MB
    float* dinv  = (float*)(ws + off); off += (size_t)BB * NN * 4;          // 64 KB

    hipMemsetAsync(rcnt, 0, (size_t)BB * NN * sizeof(int), stream);

    transpose_kernel<<<dim3(NN / 32, CINC / 32, BB), dim3(32, 8), 0, stream>>>(features, fT);
    knn_kernel<<<dim3(BB * NN), dim3(256), 0, stream>>>(xyz, idx, rcnt, rev);
    dinv_kernel<<<dim3(BB * NN / 256), dim3(256), 0, stream>>>(rcnt, dinv);
    spec_kernel<<<dim3(BB * NN), dim3(128), 0, stream>>>(fT, idx, rcnt, rev, dinv, specT);
    gemm1_kernel<<<dim3(NN / 64, COU / 64, BB), dim3(16, 16), 0, stream>>>(
        specT, W_spec, b_spec, bn_gamma, bn_beta, bn_mean, bn_var, g1T);
    gemm2_kernel<<<dim3(NN / 64, COU / 64, BB), dim3(16, 16), 0, stream>>>(
        g1T, W_low, b_low, W_high, b_high, out);
}

// Round 3
// 350.450 us; speedup vs baseline: 1.1241x; 1.1241x over previous
//
#include <hip/hip_runtime.h>
#include <math.h>

#define BB   8
#define NN   2048
#define CINC 128
#define COU  256
#define KNNK 16
#define REVCAP 64
#define SEG   8
#define SEGC  (NN / SEG)   // 256 candidates per segment

// ---------------- transpose features (B,C,N) -> fT (B,N,C) ----------------
__global__ __launch_bounds__(256) void transpose_kernel(const float* __restrict__ feat,
                                                        float* __restrict__ fT) {
    __shared__ float t[32][33];
    int b  = blockIdx.z;
    int n0 = blockIdx.x * 32, c0 = blockIdx.y * 32;
    int tx = threadIdx.x, ty = threadIdx.y;  // (32,8)
#pragma unroll
    for (int i = 0; i < 4; i++)
        t[ty + i * 8][tx] = feat[((size_t)b * CINC + c0 + ty + i * 8) * NN + n0 + tx];
    __syncthreads();
#pragma unroll
    for (int i = 0; i < 4; i++)
        fT[((size_t)b * NN + n0 + ty + i * 8) * CINC + c0 + tx] = t[tx][ty + i * 8];
}

// ---------------- KNN part: per-lane register top-16 over one segment ----------------
// lane = query, wave = one segment of 256 candidates (staged in LDS, broadcast reads).
// Distance arithmetic is bit-identical to the verified round-1 kernel:
//   sq  = (x*x + y*y) + z*z                 (plain rn ops, no FMA)
//   dot = fma(z,z', fma(y,y', rn(x*x')))    (FMA chain)
//   dist = (sq_n + sq_m) - 2*dot            (plain rn ops)
// Key = (ordered_float(dist) << 32) | idx : u64 lexicographic min == top_k tie-break.
__global__ __launch_bounds__(256) void knn_part_kernel(const float* __restrict__ xyz,
                                                       unsigned long long* __restrict__ part) {
    __shared__ float4 cand[4][SEGC];
    int b = blockIdx.z;
    int lane = threadIdx.x & 63;
    int w = threadIdx.x >> 6;                 // wave id -> segment
    int q = blockIdx.x * 64 + lane;
    int s = blockIdx.y * 4 + w;

    const float* xb = xyz + (size_t)b * 3 * NN;

    // stage 4 segments (1024 candidates) cooperatively
    int base = blockIdx.y * (4 * SEGC);
    for (int t = threadIdx.x; t < 4 * SEGC; t += 256) {
        int m = base + t;
        float x = xb[m], y = xb[NN + m], z = xb[2 * NN + m];
        float sq = __fadd_rn(__fadd_rn(__fmul_rn(x, x), __fmul_rn(y, y)), __fmul_rn(z, z));
        cand[t >> 8][t & (SEGC - 1)] = make_float4(x, y, z, sq);
    }
    __syncthreads();

    float qx = xb[q], qy = xb[NN + q], qz = xb[2 * NN + q];
    float qsq = __fadd_rn(__fadd_rn(__fmul_rn(qx, qx), __fmul_rn(qy, qy)), __fmul_rn(qz, qz));

    unsigned long long t16[16];
#pragma unroll
    for (int j = 0; j < 16; j++) t16[j] = ~0ull;

    int segbase = s * SEGC;
    for (int i = 0; i < SEGC; i++) {
        float4 c = cand[w][i];
        float dot = fmaf(qz, c.z, fmaf(qy, c.y, __fmul_rn(qx, c.x)));
        float d = __fsub_rn(__fadd_rn(qsq, c.w), __fmul_rn(2.0f, dot));
        unsigned int u = __float_as_uint(d);
        u = ((int)u < 0) ? ~u : (u | 0x80000000u);
        unsigned long long key = ((unsigned long long)u << 32) | (unsigned int)(segbase + i);
        if (key < t16[15]) {
            t16[15] = key;
#pragma unroll
            for (int j = 15; j > 0; j--) {
                unsigned long long a = t16[j - 1], bk = t16[j];
                bool sw = bk < a;
                t16[j - 1] = sw ? bk : a;
                t16[j]     = sw ? a : bk;
            }
        }
    }

    unsigned long long* po = part + (((size_t)b * NN + q) * SEG + s) * KNNK;
#pragma unroll
    for (int j = 0; j < 16; j++) po[j] = t16[j];
}

// ---------------- KNN merge: fold 8 sorted 16-lists -> final top-16 ----------------
__global__ __launch_bounds__(256) void knn_merge_kernel(const unsigned long long* __restrict__ part,
                                                        int* __restrict__ knn_idx,
                                                        int* __restrict__ revcnt,
                                                        int* __restrict__ rev) {
    int bq = blockIdx.x * 256 + threadIdx.x;   // b*NN + n
    int b = bq >> 11;
    int n = bq & (NN - 1);

    unsigned long long t16[16];
#pragma unroll
    for (int j = 0; j < 16; j++) t16[j] = ~0ull;

    const unsigned long long* pp = part + (size_t)bq * SEG * KNNK;
    for (int i = 0; i < SEG * KNNK; i++) {
        unsigned long long key = pp[i];
        if (key < t16[15]) {
            t16[15] = key;
#pragma unroll
            for (int j = 15; j > 0; j--) {
                unsigned long long a = t16[j - 1], bk = t16[j];
                bool sw = bk < a;
                t16[j - 1] = sw ? bk : a;
                t16[j]     = sw ? a : bk;
            }
        }
    }

#pragma unroll
    for (int j = 0; j < 16; j++) {
        int m = (int)(t16[j] & 0xffffffffull);
        knn_idx[(size_t)bq * KNNK + j] = m;
        int pos = atomicAdd(&revcnt[b * NN + m], 1);
        if (pos < REVCAP) rev[((size_t)(b * NN + m)) * REVCAP + pos] = n;
    }
}

// ---------------- dinv = rsqrt(D + 1e-6), D = 0.5*(K + indeg) ----------------
__global__ __launch_bounds__(256) void dinv_kernel(const int* __restrict__ revcnt,
                                                   float* __restrict__ dinv) {
    int i = blockIdx.x * 256 + threadIdx.x;
    if (i < BB * NN) {
        float D = 0.5f * (float)(KNNK + revcnt[i]);
        dinv[i] = 1.0f / sqrtf(D + 1e-6f);
    }
}

// ---------------- spec[c,n] = f[c,n] - d_n * sum_j 0.5*d_mj * f[c,mj] ----------------
__global__ __launch_bounds__(128) void spec_kernel(const float* __restrict__ fT,
                                                   const int* __restrict__ knn_idx,
                                                   const int* __restrict__ revcnt,
                                                   const int* __restrict__ rev,
                                                   const float* __restrict__ dinv,
                                                   float* __restrict__ specT) {
    __shared__ int ml[KNNK + REVCAP];
    __shared__ float wl[KNNK + REVCAP];
    __shared__ int s_cnt;

    int bn = blockIdx.x;           // b*NN + n
    int b = bn >> 11;
    int tid = threadIdx.x;

    if (tid == 0) {
        int c = revcnt[bn];
        s_cnt = c < REVCAP ? c : REVCAP;
    }
    __syncthreads();
    int cnt = s_cnt;
    if (tid < KNNK) ml[tid] = knn_idx[(size_t)bn * KNNK + tid];
    if (tid < cnt) ml[KNNK + tid] = rev[(size_t)bn * REVCAP + tid];
    __syncthreads();
    int total = KNNK + cnt;
    if (tid < total) wl[tid] = 0.5f * dinv[b * NN + ml[tid]];
    __syncthreads();

    float dn = dinv[bn];
    float acc = 0.0f;
    for (int j = 0; j < total; j++)
        acc = fmaf(wl[j], fT[((size_t)b * NN + ml[j]) * CINC + tid], acc);
    float f0 = fT[(size_t)bn * CINC + tid];
    specT[(size_t)bn * CINC + tid] = f0 - dn * acc;
}

// ---------------- GEMM1: g1 = gelu(bn(W_spec @ spec + b)) , layout (b,n,o) ----------------
__global__ __launch_bounds__(256) void gemm1_kernel(const float* __restrict__ specT,
                                                    const float* __restrict__ Wspec,
                                                    const float* __restrict__ bspec,
                                                    const float* __restrict__ gamma,
                                                    const float* __restrict__ beta,
                                                    const float* __restrict__ mean,
                                                    const float* __restrict__ var,
                                                    float* __restrict__ g1T) {
    __shared__ float Sa[64][65];
    __shared__ float Sb[64][65];
    int n0 = blockIdx.x * 64, o0 = blockIdx.y * 64, b = blockIdx.z;
    int tx = threadIdx.x, ty = threadIdx.y;
    int tid = ty * 16 + tx;

    float acc[4][4] = {};
    for (int kk = 0; kk < CINC; kk += 64) {
        __syncthreads();
        for (int i = tid; i < 64 * 64; i += 256) {
            int r = i >> 6, k = i & 63;
            Sa[r][k] = specT[((size_t)b * NN + n0 + r) * CINC + kk + k];
            Sb[r][k] = Wspec[(size_t)(o0 + r) * CINC + kk + k];
        }
        __syncthreads();
#pragma unroll 8
        for (int k = 0; k < 64; k++) {
            float a0 = Sa[ty * 4 + 0][k], a1 = Sa[ty * 4 + 1][k];
            float a2 = Sa[ty * 4 + 2][k], a3 = Sa[ty * 4 + 3][k];
            float w0 = Sb[tx * 4 + 0][k], w1 = Sb[tx * 4 + 1][k];
            float w2 = Sb[tx * 4 + 2][k], w3 = Sb[tx * 4 + 3][k];
            acc[0][0] = fmaf(a0, w0, acc[0][0]); acc[0][1] = fmaf(a0, w1, acc[0][1]);
            acc[0][2] = fmaf(a0, w2, acc[0][2]); acc[0][3] = fmaf(a0, w3, acc[0][3]);
            acc[1][0] = fmaf(a1, w0, acc[1][0]); acc[1][1] = fmaf(a1, w1, acc[1][1]);
            acc[1][2] = fmaf(a1, w2, acc[1][2]); acc[1][3] = fmaf(a1, w3, acc[1][3]);
            acc[2][0] = fmaf(a2, w0, acc[2][0]); acc[2][1] = fmaf(a2, w1, acc[2][1]);
            acc[2][2] = fmaf(a2, w2, acc[2][2]); acc[2][3] = fmaf(a2, w3, acc[2][3]);
            acc[3][0] = fmaf(a3, w0, acc[3][0]); acc[3][1] = fmaf(a3, w1, acc[3][1]);
            acc[3][2] = fmaf(a3, w2, acc[3][2]); acc[3][3] = fmaf(a3, w3, acc[3][3]);
        }
    }
#pragma unroll
    for (int j = 0; j < 4; j++) {
        int o = o0 + tx * 4 + j;
        float sc = 1.0f / sqrtf(var[o] + 1e-5f);
        float ga = gamma[o], be = beta[o], mu = mean[o], bs = bspec[o];
#pragma unroll
        for (int i = 0; i < 4; i++) {
            float y = acc[i][j] + bs;
            y = (y - mu) * sc;
            y = y * ga + be;
            float g = 0.5f * y * (1.0f + erff(y * 0.70710678118654752440f));
            g1T[((size_t)b * NN + n0 + ty * 4 + i) * COU + o] = g;
        }
    }
}

// ---------------- GEMM2: out[b,o,n] = W2[o,:] @ g1[b,n,:] + b2[o] ----------------
__global__ __launch_bounds__(256) void gemm2_kernel(const float* __restrict__ g1T,
                                                    const float* __restrict__ Wlow,
                                                    const float* __restrict__ blow,
                                                    const float* __restrict__ Whigh,
                                                    const float* __restrict__ bhigh,
                                                    float* __restrict__ out) {
    __shared__ float Ga[64][65];
    __shared__ float Wb[64][65];
    int n0 = blockIdx.x * 64, o0 = blockIdx.y * 64, b = blockIdx.z;
    int tx = threadIdx.x, ty = threadIdx.y;
    int tid = ty * 16 + tx;

    float acc[4][4] = {};
    for (int kk = 0; kk < COU; kk += 64) {
        __syncthreads();
        for (int i = tid; i < 64 * 64; i += 256) {
            int r = i >> 6, k = i & 63;
            Ga[r][k] = g1T[((size_t)b * NN + n0 + r) * COU + kk + k];
            int o = o0 + r;
            Wb[r][k] = (o < 128) ? Wlow[(size_t)o * COU + kk + k]
                                 : Whigh[(size_t)(o - 128) * COU + kk + k];
        }
        __syncthreads();
#pragma unroll 8
        for (int k = 0; k < 64; k++) {
            float a0 = Ga[ty * 4 + 0][k], a1 = Ga[ty * 4 + 1][k];
            float a2 = Ga[ty * 4 + 2][k], a3 = Ga[ty * 4 + 3][k];
            float w0 = Wb[tx * 4 + 0][k], w1 = Wb[tx * 4 + 1][k];
            float w2 = Wb[tx * 4 + 2][k], w3 = Wb[tx * 4 + 3][k];
            acc[0][0] = fmaf(a0, w0, acc[0][0]); acc[0][1] = fmaf(a0, w1, acc[0][1]);
            acc[0][2] = fmaf(a0, w2, acc[0][2]); acc[0][3] = fmaf(a0, w3, acc[0][3]);
            acc[1][0] = fmaf(a1, w0, acc[1][0]); acc[1][1] = fmaf(a1, w1, acc[1][1]);
            acc[1][2] = fmaf(a1, w2, acc[1][2]); acc[1][3] = fmaf(a1, w3, acc[1][3]);
            acc[2][0] = fmaf(a2, w0, acc[2][0]); acc[2][1] = fmaf(a2, w1, acc[2][1]);
            acc[2][2] = fmaf(a2, w2, acc[2][2]); acc[2][3] = fmaf(a2, w3, acc[2][3]);
            acc[3][0] = fmaf(a3, w0, acc[3][0]); acc[3][1] = fmaf(a3, w1, acc[3][1]);
            acc[3][2] = fmaf(a3, w2, acc[3][2]); acc[3][3] = fmaf(a3, w3, acc[3][3]);
        }
    }
#pragma unroll
    for (int j = 0; j < 4; j++) {
        int o = o0 + tx * 4 + j;
        float bias = (o < 128) ? blow[o] : bhigh[o - 128];
        float4 v;
        v.x = acc[0][j] + bias;
        v.y = acc[1][j] + bias;
        v.z = acc[2][j] + bias;
        v.w = acc[3][j] + bias;
        *(float4*)&out[((size_t)b * COU + o) * NN + n0 + ty * 4] = v;
    }
}

extern "C" void kernel_launch(void* const* d_in, const int* in_sizes, int n_in,
                              void* d_out, int out_size, void* d_ws, size_t ws_size,
                              hipStream_t stream) {
    const float* xyz      = (const float*)d_in[0];
    const float* features = (const float*)d_in[1];
    const float* W_spec   = (const float*)d_in[2];
    const float* b_spec   = (const float*)d_in[3];
    const float* bn_gamma = (const float*)d_in[4];
    const float* bn_beta  = (const float*)d_in[5];
    const float* bn_mean  = (const float*)d_in[6];
    const float* bn_var   = (const float*)d_in[7];
    const float* W_low    = (const float*)d_in[8];
    const float* b_low    = (const float*)d_in[9];
    const float* W_high   = (const float*)d_in[10];
    const float* b_high   = (const float*)d_in[11];
    float* out = (float*)d_out;

    char* ws = (char*)d_ws;
    size_t off = 0;
    float* fT    = (float*)(ws + off); off += (size_t)BB * NN * CINC * 4;            // 8 MB
    float* specT = (float*)(ws + off); off += (size_t)BB * NN * CINC * 4;            // 8 MB
    float* g1T   = (float*)(ws + off); off += (size_t)BB * NN * COU  * 4;            // 16 MB
    int*   idx   = (int*)  (ws + off); off += (size_t)BB * NN * KNNK * 4;            // 1 MB
    int*   rcnt  = (int*)  (ws + off); off += (size_t)BB * NN * 4;                   // 64 KB
    int*   rev   = (int*)  (ws + off); off += (size_t)BB * NN * REVCAP * 4;          // 4 MB
    float* dinv  = (float*)(ws + off); off += (size_t)BB * NN * 4;                   // 64 KB
    unsigned long long* part = (unsigned long long*)(ws + off);
    off += (size_t)BB * NN * SEG * KNNK * 8;                                         // 16 MB

    hipMemsetAsync(rcnt, 0, (size_t)BB * NN * sizeof(int), stream);

    transpose_kernel<<<dim3(NN / 32, CINC / 32, BB), dim3(32, 8), 0, stream>>>(features, fT);
    knn_part_kernel<<<dim3(NN / 64, SEG / 4, BB), dim3(256), 0, stream>>>(xyz, part);
    knn_merge_kernel<<<dim3(BB * NN / 256), dim3(256), 0, stream>>>(part, idx, rcnt, rev);
    dinv_kernel<<<dim3(BB * NN / 256), dim3(256), 0, stream>>>(rcnt, dinv);
    spec_kernel<<<dim3(BB * NN), dim3(128), 0, stream>>>(fT, idx, rcnt, rev, dinv, specT);
    gemm1_kernel<<<dim3(NN / 64, COU / 64, BB), dim3(16, 16), 0, stream>>>(
        specT, W_spec, b_spec, bn_gamma, bn_beta, bn_mean, bn_var, g1T);
    gemm2_kernel<<<dim3(NN / 64, COU / 64, BB), dim3(16, 16), 0, stream>>>(
        g1T, W_low, b_low, W_high, b_high, out);
}